// Round 16
// baseline (81.104 us; speedup 1.0000x reference)
//
#include <hip/hip_runtime.h>
#include <hip/hip_bf16.h>
#include <math.h>

#define B 4
#define L 512
#define H 512
#define NH 8
#define DK 64
#define RIN 53
#define RHID 32

using short8 = __attribute__((ext_vector_type(8))) short;
using ushort8v = __attribute__((ext_vector_type(8))) unsigned short;
using f32x4 = __attribute__((ext_vector_type(4))) float;

__device__ __forceinline__ unsigned short cvt_bf16(float f) {
  __hip_bfloat16 h = __float2bfloat16(f);  // RNE; compiler emits cvt_pk pairs
  return __builtin_bit_cast(unsigned short, h);
}
__device__ __forceinline__ float bf2f(unsigned short u) {
  return __uint_as_float((unsigned)u << 16);
}

// ---------------------------------------------------------------------------
// prep: blocks 0..3 = per-batch mask compaction; 4..131 = W transposes;
// 132..135 = xsum[b][k] = sum_j x[b][j][k]  (for dead-row meanV)
// ---------------------------------------------------------------------------
__global__ __launch_bounds__(512) void prep_kernel(
    const int* __restrict__ mask, int* __restrict__ jidx, int* __restrict__ nv,
    const float* __restrict__ Wv, const float* __restrict__ Wo,
    unsigned short* __restrict__ WvT, unsigned short* __restrict__ WoT,
    const float* __restrict__ x, float* __restrict__ xsum) {
  const int bid = blockIdx.x;
  const int tid = threadIdx.x;
  if (bid < 4) {
    const int b = bid;
    const int lane = tid & 63, wv = tid >> 6;
    __shared__ int wtot[8], woff[8];
    const int m = (mask[b * 512 + tid] != 0);
    const unsigned long long bal = __ballot(m);
    const int lpre = __popcll(bal & ((1ull << lane) - 1ull));
    if (lane == 0) wtot[wv] = __popcll(bal);
    __syncthreads();
    if (tid == 0) {
      int acc = 0;
#pragma unroll
      for (int q = 0; q < 8; ++q) {
        woff[q] = acc;
        acc += wtot[q];
      }
      nv[b] = acc;
    }
    __syncthreads();
    if (m) jidx[b * 512 + woff[wv] + lpre] = tid;
    return;
  }
  if (bid >= 132) {
    // xsum: column sums of x[b]
    const int b = bid - 132;
    float acc = 0.f;
    for (int j = 0; j < 512; ++j) acc += x[((size_t)(b * 512) + j) * 512 + tid];
    xsum[b * 512 + tid] = acc;
    return;
  }
  const int t = bid - 4;      // 0..127
  const int matsel = t >> 6;  // 0 = Wv, 1 = Wo
  const int tile = t & 63;
  const float* W = matsel ? Wo : Wv;
  unsigned short* WT = matsel ? WoT : WvT;
  const int k0 = (tile & 7) * 64, n0 = (tile >> 3) * 64;
  __shared__ float sT[64][65];
  {
    const int r = tid >> 3, c0 = (tid & 7) * 8;
    const float4 v0 = *(const float4*)(W + (size_t)(k0 + r) * 512 + n0 + c0);
    const float4 v1 = *(const float4*)(W + (size_t)(k0 + r) * 512 + n0 + c0 + 4);
    sT[r][c0] = v0.x; sT[r][c0 + 1] = v0.y; sT[r][c0 + 2] = v0.z; sT[r][c0 + 3] = v0.w;
    sT[r][c0 + 4] = v1.x; sT[r][c0 + 5] = v1.y; sT[r][c0 + 6] = v1.z; sT[r][c0 + 7] = v1.w;
  }
  __syncthreads();
  {
    const int n = tid >> 3, c0 = (tid & 7) * 8;
    ushort8v o;
#pragma unroll
    for (int cc = 0; cc < 8; ++cc) o[cc] = cvt_bf16(sT[c0 + cc][n]);
    *(ushort8v*)(WT + (size_t)(n0 + n) * 512 + k0 + c0) = o;
  }
}

// ---------------------------------------------------------------------------
// bf16 MFMA GEMM core: C[32 m x 64 n], K up to 512 (runtime kend, multiple of
// BK), templated BK (64 or 128), 256 thr.
// AMODE 0: A = bf16 [m][k] base pointer.  AMODE 1: A = f32 PER-THREAD ROW
// pointer (requires BK=64 so NA==1; row = tid>>3 folded in by caller).
// OMODE 1: bf16 store, with optional dead-row meanV override.
// OMODE 2: bf16 transposed store.
// NOTE (R8/R11/R14): GEMM phases need >=256 blocks; many small 256-thr
// blocks with cheap barriers beat fewer wide blocks.
// ---------------------------------------------------------------------------
template <int AMODE, int OMODE, int BK>
__device__ __forceinline__ void gemm32x64(
    char* __restrict__ smem, const void* __restrict__ Aq, int lda,
    const unsigned short* __restrict__ Bs, int ldb,
    const float* __restrict__ bias, void* __restrict__ Cp, int ldc,
    int kend = 512, const int* __restrict__ maskRow = nullptr,
    const float* __restrict__ meanVslice = nullptr, bool alldead = false) {
  constexpr int KS = BK / 8;   // ushort8 slots per row
  constexpr int STR = BK + 8;  // padded row stride (shorts)
  constexpr int NA = 32 * KS / 256;
  constexpr int NB = 64 * KS / 256;
  unsigned short* sA = (unsigned short*)smem;
  unsigned short* sB = (unsigned short*)(smem + 32 * STR * 2);
  float(*sC)[68] = (float(*)[68])smem;
  const int tid = threadIdx.x;
  const int w = tid >> 6, l = tid & 63, g = l >> 4, a = l & 15;
  const int wm = (w >> 1) * 16, wn = (w & 1) * 32;
  f32x4 acc0 = {}, acc1 = {};

  ushort8v aR[NA], bR[NB];
  auto loadA = [&](int k0) {
#pragma unroll
    for (int q = 0; q < NA; ++q) {
      const int s = tid + q * 256;
      const int row = s / KS, kk = s % KS;
      if constexpr (AMODE == 1) {
        // per-thread row pointer (NA==1): row folded in by caller
        const float* p = (const float*)Aq + k0 + kk * 8;
        const float4 v0 = *(const float4*)p;
        const float4 v1 = *(const float4*)(p + 4);
        ushort8v r;
        r[0] = cvt_bf16(v0.x); r[1] = cvt_bf16(v0.y);
        r[2] = cvt_bf16(v0.z); r[3] = cvt_bf16(v0.w);
        r[4] = cvt_bf16(v1.x); r[5] = cvt_bf16(v1.y);
        r[6] = cvt_bf16(v1.z); r[7] = cvt_bf16(v1.w);
        aR[q] = r;
      } else {
        const unsigned short* Ab = (const unsigned short*)Aq;
        aR[q] = *(const ushort8v*)(Ab + (size_t)row * lda + k0 + kk * 8);
      }
    }
  };
  auto loadB = [&](int k0) {
#pragma unroll
    for (int q = 0; q < NB; ++q) {
      const int s = tid + q * 256;
      const int row = s / KS, kk = s % KS;
      bR[q] = *(const ushort8v*)(Bs + (size_t)row * ldb + k0 + kk * 8);
    }
  };
  auto stage = [&]() {
#pragma unroll
    for (int q = 0; q < NA; ++q) {
      const int s = tid + q * 256;
      *(ushort8v*)(&sA[(s / KS) * STR + (s % KS) * 8]) = aR[q];
    }
#pragma unroll
    for (int q = 0; q < NB; ++q) {
      const int s = tid + q * 256;
      *(ushort8v*)(&sB[(s / KS) * STR + (s % KS) * 8]) = bR[q];
    }
  };

  if (kend > 0) {
    loadA(0);
    loadB(0);
  }
  for (int k0 = 0; k0 < kend; k0 += BK) {
    stage();
    __syncthreads();
    if (k0 + BK < kend) {
      loadA(k0 + BK);
      loadB(k0 + BK);
    }
#pragma unroll
    for (int ks = 0; ks < BK / 32; ++ks) {
      const short8 af = *(const short8*)(&sA[(wm + a) * STR + ks * 32 + g * 8]);
      const short8 bf0 = *(const short8*)(&sB[(wn + a) * STR + ks * 32 + g * 8]);
      const short8 bf1 =
          *(const short8*)(&sB[(wn + 16 + a) * STR + ks * 32 + g * 8]);
      acc0 = __builtin_amdgcn_mfma_f32_16x16x32_bf16(af, bf0, acc0, 0, 0, 0);
      acc1 = __builtin_amdgcn_mfma_f32_16x16x32_bf16(af, bf1, acc1, 0, 0, 0);
    }
    __syncthreads();
  }

#pragma unroll
  for (int r = 0; r < 4; ++r) {
    sC[wm + g * 4 + r][wn + a] = acc0[r];
    sC[wm + g * 4 + r][wn + 16 + a] = acc1[r];
  }
  __syncthreads();

  if constexpr (OMODE == 2) {
    const int n = tid >> 2, iq = (tid & 3) * 8;
    const float bv = bias ? bias[n] : 0.f;
    ushort8v o;
#pragma unroll
    for (int cc = 0; cc < 8; ++cc) o[cc] = cvt_bf16(sC[iq + cc][n] + bv);
    *(ushort8v*)((unsigned short*)Cp + (size_t)n * ldc + iq) = o;
  } else {
    const int m = tid >> 3, c8 = (tid & 7) * 8;
    const bool dead = alldead || (maskRow && maskRow[m] == 0);
    ushort8v o;
#pragma unroll
    for (int cc = 0; cc < 8; ++cc) {
      float v = sC[m][c8 + cc];
      if (bias) v += bias[c8 + cc];
      if (maskRow && dead) v = meanVslice[c8 + cc];
      o[cc] = cvt_bf16(v);
    }
    *(ushort8v*)((unsigned short*)Cp + (size_t)m * ldc + c8) = o;
  }
}

#define GEMM64_SMEM 13824   // 32*72*2 + 64*72*2
#define GEMM128_SMEM 26112  // 32*136*2 + 64*136*2

// ---------------------------------------------------------------------------
// Fused launch: blocks 0..2047 = scores (compacted output), 2048..2559 =
// valTc gather-GEMM (BK64), 2560..2563 = meanV.
// ---------------------------------------------------------------------------
#define FUSED_SMEM 15616
__global__ __launch_bounds__(256) void fused_scores_value_kernel(
    const float* __restrict__ refCov, const int* __restrict__ mask,
    const int* __restrict__ jidx, const int* __restrict__ nvArr,
    const float* __restrict__ W1, const float* __restrict__ b1,
    const float* __restrict__ W2, const float* __restrict__ b2,
    unsigned short* __restrict__ attnb, const float* __restrict__ x,
    const unsigned short* __restrict__ WvT, const float* __restrict__ bv,
    unsigned short* __restrict__ valT, const float* __restrict__ xsum,
    float* __restrict__ meanV) {
  __shared__ __align__(16) char smem[FUSED_SMEM];
  const int tid = threadIdx.x;

  if (blockIdx.x >= 2560) {
    // ---- meanV[b][n] = (1/512) * xsum[b] . WvT[n] + bv[n] ----
    const int b = blockIdx.x - 2560;
    float* sX = (float*)smem;  // 512 f32
    sX[tid] = xsum[b * 512 + tid];
    sX[tid + 256] = xsum[b * 512 + 256 + tid];
    __syncthreads();
#pragma unroll
    for (int p = 0; p < 2; ++p) {
      const int n = tid * 2 + p;
      float acc = 0.f;
      for (int kc = 0; kc < 64; ++kc) {
        const ushort8v wv = *(const ushort8v*)(WvT + (size_t)n * 512 + kc * 8);
#pragma unroll
        for (int e = 0; e < 8; ++e) acc += sX[kc * 8 + e] * bf2f(wv[e]);
      }
      meanV[b * 512 + n] = acc * (1.f / 512.f) + bv[n];
    }
    return;
  }

  if (blockIdx.x >= 2048) {
    // ---- valTc = gathered (x @ WvT + bv)^T over compacted s ----
    const int gb = blockIdx.x - 2048;  // 0..511
    const int n0 = (gb & 7) * 64;
    const int m0 = (gb >> 3) * 32;
    const int b = m0 >> 9, s0 = m0 & 511;
    const int nvb = nvArr[b];
    const int row = tid >> 3;
    const int s = s0 + row;
    const int srcj = (s < nvb) ? jidx[b * 512 + s] : 0;
    const float* arow = x + ((size_t)(b * 512) + srcj) * 512;
    gemm32x64<1, 2, 64>(smem, arow, 512, WvT + (size_t)n0 * 512, 512, bv + n0,
                        valT + (size_t)b * 262144 + (size_t)n0 * 512 + s0, 512);
    return;
  }

  // ---- scores path (compacted-column output) ----
  unsigned short* sH1 = (unsigned short*)smem;            // [4][16][40]
  int* sJ = (int*)(smem + 5120);                          // [512]
  unsigned short* sOut = (unsigned short*)(smem + 7168);  // [8][512]
  float(*redbuf)[16] = (float(*)[16])(smem + 15360);      // [4][16]

  const int b = blockIdx.x >> 9;
  const int i = blockIdx.x & (L - 1);
  const int w = tid >> 6;
  const int l = tid & 63;
  const int g = l >> 4;
  const int a = l & 15;

  const int mi = mask[b * L + i];
  const int nv = nvArr[b];
  const int kend = (nv + 127) & ~127;  // columns attn_value will read

  if (mi == 0 || nv == 0) {
    // dead row: compacted attn row = zeros (ctx comes from meanV)
    if (kend > 0) {
      const ushort8v z{};
      const int h = tid >> 5, off = (tid & 31) * 16;
      if (off < kend) {
        unsigned short* dst = attnb + ((size_t)(b * NH + h) * L + i) * L + off;
        *(ushort8v*)dst = z;
        *(ushort8v*)(dst + 8) = z;
      }
    }
    return;
  }

  sJ[tid] = jidx[b * 512 + tid];
  sJ[tid + 256] = jidx[b * 512 + 256 + tid];

  short8 w1f[2][2];
#pragma unroll
  for (int ks = 0; ks < 2; ++ks)
#pragma unroll
    for (int nt = 0; nt < 2; ++nt)
#pragma unroll
      for (int e = 0; e < 8; ++e) {
        const int k = ks * 32 + g * 8 + e;
        w1f[ks][nt][e] =
            (k < RIN) ? (short)cvt_bf16(W1[k * RHID + nt * 16 + a]) : (short)0;
      }
  short8 w2f;
#pragma unroll
  for (int e = 0; e < 8; ++e) {
    const int k = g * 8 + e;
    w2f[e] = (a < NH) ? (short)cvt_bf16(W2[k * NH + a]) : (short)0;
  }
  const float b1v0 = b1[a];
  const float b1v1 = b1[16 + a];
  const float b2v = (a < NH) ? b2[a] : 0.f;

  __syncthreads();  // sJ ready

  const int NT = (nv + 15) >> 4;  // <= 32
  f32x4 sc[8];

#pragma unroll
  for (int mt = 0; mt < 8; ++mt) {
    const int t = mt * 4 + w;
    if (t >= NT) continue;
    const int s = t * 16 + a;
    const int j = sJ[(s < nv) ? s : (nv - 1)];
    const float* rp = refCov + ((size_t)((b << 9) + i) * 512 + j) * RIN;

    const float4 u0 = *(const float4*)(rp + g * 8);
    const float4 u1 = *(const float4*)(rp + g * 8 + 4);
    const int base0 = (g < 3) ? (32 + g * 8) : 32;
    const int base1 = (g == 0) ? 36 : (g == 1) ? 44 : 49;
    const float4 v0 = *(const float4*)(rp + base0);
    const float4 v1 = *(const float4*)(rp + base1);
    float t1[8];
    if (g < 3) {
      t1[0] = v0.x; t1[1] = v0.y; t1[2] = v0.z; t1[3] = v0.w;
    } else {
      t1[0] = 0.f; t1[1] = 0.f; t1[2] = 0.f; t1[3] = 0.f;
    }
    if (g < 2) {
      t1[4] = v1.x; t1[5] = v1.y; t1[6] = v1.z; t1[7] = v1.w;
    } else if (g == 2) {
      t1[4] = v1.w;  // k = 52
      t1[5] = 0.f; t1[6] = 0.f; t1[7] = 0.f;
    } else {
      t1[4] = 0.f; t1[5] = 0.f; t1[6] = 0.f; t1[7] = 0.f;
    }
    short8 af0, af1;
    af0[0] = (short)cvt_bf16(u0.x); af0[1] = (short)cvt_bf16(u0.y);
    af0[2] = (short)cvt_bf16(u0.z); af0[3] = (short)cvt_bf16(u0.w);
    af0[4] = (short)cvt_bf16(u1.x); af0[5] = (short)cvt_bf16(u1.y);
    af0[6] = (short)cvt_bf16(u1.z); af0[7] = (short)cvt_bf16(u1.w);
#pragma unroll
    for (int e = 0; e < 8; ++e) af1[e] = (short)cvt_bf16(t1[e]);

    f32x4 h0 = f32x4{b1v0, b1v0, b1v0, b1v0};
    f32x4 h1v = f32x4{b1v1, b1v1, b1v1, b1v1};
    h0 = __builtin_amdgcn_mfma_f32_16x16x32_bf16(af0, w1f[0][0], h0, 0, 0, 0);
    h1v = __builtin_amdgcn_mfma_f32_16x16x32_bf16(af0, w1f[0][1], h1v, 0, 0, 0);
    h0 = __builtin_amdgcn_mfma_f32_16x16x32_bf16(af1, w1f[1][0], h0, 0, 0, 0);
    h1v = __builtin_amdgcn_mfma_f32_16x16x32_bf16(af1, w1f[1][1], h1v, 0, 0, 0);

#pragma unroll
    for (int r = 0; r < 4; ++r) {
      sH1[(w * 16 + g * 4 + r) * 40 + a] = cvt_bf16(fmaxf(h0[r], 0.f));
      sH1[(w * 16 + g * 4 + r) * 40 + 16 + a] = cvt_bf16(fmaxf(h1v[r], 0.f));
    }

    const short8 af2 = *(const short8*)(&sH1[(w * 16 + a) * 40 + g * 8]);
    f32x4 acc = f32x4{b2v, b2v, b2v, b2v};
    sc[mt] = __builtin_amdgcn_mfma_f32_16x16x32_bf16(af2, w2f, acc, 0, 0, 0);
  }

  float mx = -INFINITY;
#pragma unroll
  for (int mt = 0; mt < 8; ++mt) {
    const int t = mt * 4 + w;
    if (t >= NT) continue;
#pragma unroll
    for (int r = 0; r < 4; ++r) {
      const int s = t * 16 + g * 4 + r;
      if (s < nv) mx = fmaxf(mx, sc[mt][r]);
    }
  }
  mx = fmaxf(mx, __shfl_xor(mx, 16, 64));
  mx = fmaxf(mx, __shfl_xor(mx, 32, 64));
  if (g == 0) redbuf[w][a] = mx;
  __syncthreads();
  const float rmax = fmaxf(fmaxf(redbuf[0][a], redbuf[1][a]),
                           fmaxf(redbuf[2][a], redbuf[3][a]));
  __syncthreads();

  float lsum = 0.f;
#pragma unroll
  for (int mt = 0; mt < 8; ++mt) {
    const int t = mt * 4 + w;
    if (t >= NT) continue;
#pragma unroll
    for (int r = 0; r < 4; ++r) {
      const int s = t * 16 + g * 4 + r;
      const float e = (s < nv) ? __expf(sc[mt][r] - rmax) : 0.f;
      sc[mt][r] = e;
      lsum += e;
    }
  }
  lsum += __shfl_xor(lsum, 16, 64);
  lsum += __shfl_xor(lsum, 32, 64);
  if (g == 0) redbuf[w][a] = lsum;
  __syncthreads();
  const float rsum = redbuf[0][a] + redbuf[1][a] + redbuf[2][a] + redbuf[3][a];
  const float inv = 1.f / rsum;

  {
    const ushort8v z{};
    *(ushort8v*)(&sOut[tid * 16]) = z;
    *(ushort8v*)(&sOut[tid * 16 + 8]) = z;
  }
  __syncthreads();
  if (a < NH) {
#pragma unroll
    for (int mt = 0; mt < 8; ++mt) {
      const int t = mt * 4 + w;
      if (t >= NT) continue;
#pragma unroll
      for (int r = 0; r < 4; ++r) {
        const int s = t * 16 + g * 4 + r;
        if (s < nv) sOut[a * 512 + s] = cvt_bf16(sc[mt][r] * inv);  // compacted
      }
    }
  }
  __syncthreads();
  {
    const int h = tid >> 5, off = (tid & 31) * 16;
    if (off < kend) {
      unsigned short* dst = attnb + ((size_t)(b * NH + h) * L + i) * L + off;
      *(ushort8v*)dst = *(const ushort8v*)(&sOut[h * 512 + off]);
      *(ushort8v*)(dst + 8) = *(const ushort8v*)(&sOut[h * 512 + off + 8]);
    }
  }
}

// ctx[b,i,h*64+d] = sum_s attnc[b,h,i,s] * valTc[b][h*64+d][s]  (K = kend),
// dead rows -> meanV.
__global__ __launch_bounds__(256) void attn_value_kernel(
    const unsigned short* __restrict__ attnb,
    const unsigned short* __restrict__ valT, const int* __restrict__ mask,
    const int* __restrict__ nvArr, const float* __restrict__ meanV,
    unsigned short* __restrict__ ctx) {
  __shared__ __align__(16) char smem[GEMM128_SMEM];
  const int bid = blockIdx.x;  // it(16) x h(8) x b(4)
  const int it = bid & 15, h = (bid >> 4) & 7, b = bid >> 7;
  const int i0 = it * 32;
  const int nvb = nvArr[b];
  const int kend = (nvb + 127) & ~127;
  gemm32x64<0, 1, 128>(smem, attnb + ((size_t)((b * 8 + h) * 512 + i0)) * 512,
                       512, valT + (size_t)b * 262144 + (size_t)(h * 64) * 512,
                       512, nullptr,
                       ctx + ((size_t)(b * 512 + i0)) * 512 + h * 64, 512, kend,
                       mask + b * 512 + i0, meanV + b * 512 + h * 64,
                       nvb == 0);
}

// proj = ctx @ WoT + bo  (bf16 out, BK=128), grid (8, 64)
__global__ __launch_bounds__(256) void gemm_proj_kernel(
    const unsigned short* __restrict__ ctx,
    const unsigned short* __restrict__ WoT, const float* __restrict__ bo,
    unsigned short* __restrict__ proj) {
  __shared__ __align__(16) char smem[GEMM128_SMEM];
  const int n0 = blockIdx.x * 64;
  const int m0 = blockIdx.y * 32;
  gemm32x64<0, 1, 128>(smem, ctx + (size_t)m0 * 512, 512,
                       WoT + (size_t)n0 * 512, 512, bo + n0,
                       proj + (size_t)m0 * 512 + n0, 512);
}

// ---------------------------------------------------------------------------
// out = LN(x + proj) * gamma + beta.  2 rows per 256-thr block (grid 1024).
// ---------------------------------------------------------------------------
__global__ __launch_bounds__(256) void residual_ln_kernel(
    const float* __restrict__ x, const unsigned short* __restrict__ proj,
    const float* __restrict__ gamma, const float* __restrict__ beta,
    float* __restrict__ out) {
  const int tid = threadIdx.x;
  const int rh = tid >> 7;  // row half (0/1)
  const int q = tid & 127;  // float4 index within row
  const int row = blockIdx.x * 2 + rh;
  __shared__ float redS[4], redQ[4];

  const float4 xv = *(const float4*)(x + (size_t)row * H + q * 4);
  const ushort4 pv = *(const ushort4*)(proj + (size_t)row * H + q * 4);
  float y[4] = {xv.x + bf2f(pv.x), xv.y + bf2f(pv.y), xv.z + bf2f(pv.z),
                xv.w + bf2f(pv.w)};
  float ls = y[0] + y[1] + y[2] + y[3];
  float lq = y[0] * y[0] + y[1] * y[1] + y[2] * y[2] + y[3] * y[3];
#pragma unroll
  for (int off = 32; off > 0; off >>= 1) {
    ls += __shfl_xor(ls, off, 64);
    lq += __shfl_xor(lq, off, 64);
  }
  const int wave = tid >> 6, lane = tid & 63;
  if (lane == 0) {
    redS[wave] = ls;
    redQ[wave] = lq;
  }
  __syncthreads();
  const float sum = redS[rh * 2] + redS[rh * 2 + 1];
  const float sq = redQ[rh * 2] + redQ[rh * 2 + 1];
  const float mu = sum * (1.f / H);
  const float var = sq * (1.f / H) - mu * mu;
  const float inv = rsqrtf(var + 1e-5f);
  const float4 gm = *(const float4*)(gamma + q * 4);
  const float4 bt = *(const float4*)(beta + q * 4);
  float4 o;
  o.x = (y[0] - mu) * inv * gm.x + bt.x;
  o.y = (y[1] - mu) * inv * gm.y + bt.y;
  o.z = (y[2] - mu) * inv * gm.z + bt.z;
  o.w = (y[3] - mu) * inv * gm.w + bt.w;
  *(float4*)(out + (size_t)row * H + q * 4) = o;
}

extern "C" void kernel_launch(void* const* d_in, const int* in_sizes, int n_in,
                              void* d_out, int out_size, void* d_ws,
                              size_t ws_size, hipStream_t stream) {
  const float* x = (const float*)d_in[0];
  const int* mask = (const int*)d_in[1];
  const float* refCov = (const float*)d_in[2];
  const float* Wv = (const float*)d_in[3];
  const float* bv = (const float*)d_in[4];
  const float* W1 = (const float*)d_in[5];
  const float* b1 = (const float*)d_in[6];
  const float* W2 = (const float*)d_in[7];
  const float* b2 = (const float*)d_in[8];
  const float* Wo = (const float*)d_in[9];
  const float* bo = (const float*)d_in[10];
  const float* gamma = (const float*)d_in[11];
  const float* beta = (const float*)d_in[12];
  float* out = (float*)d_out;

  const size_t n_attn = (size_t)B * NH * L * L;  // 8388608 (bf16)
  const size_t n_blh = (size_t)B * L * H;        // 1048576
  const size_t n_w = (size_t)H * H;              // 262144
  unsigned short* attnb = (unsigned short*)d_ws;
  unsigned short* valT = attnb + n_attn;
  unsigned short* ctx = valT + n_blh;
  unsigned short* WvT = ctx + n_blh;
  unsigned short* WoT = WvT + n_w;
  unsigned short* proj = WoT + n_w;  // bf16
  int* jidx = (int*)(proj + n_blh);
  int* nv = jidx + B * L;
  float* xsum = (float*)(nv + B);
  float* meanV = xsum + B * H;
  const size_t needed = (n_attn + 3 * n_blh + 2 * n_w) * 2 +
                        (B * L + B) * 4 + 2 * B * H * 4;
  if (ws_size < needed) return;

  const int M = B * L;  // 2048

  // 0. compaction + W transposes + xsum
  prep_kernel<<<136, 512, 0, stream>>>(mask, jidx, nv, Wv, Wo, WvT, WoT, x,
                                       xsum);
  // 1. scores (compacted) + valTc gather-GEMM + meanV, one launch
  fused_scores_value_kernel<<<2564, 256, 0, stream>>>(
      refCov, mask, jidx, nv, W1, b1, W2, b2, attnb, x, WvT, bv, valT, xsum,
      meanV);
  // 2. ctx = attnc @ valTc  (K = kend), dead rows -> meanV
  attn_value_kernel<<<512, 256, 0, stream>>>(attnb, valT, mask, nv, meanV, ctx);
  // 3. proj = ctx @ WoT + bo  (bf16, BK=128, 512 blocks)
  gemm_proj_kernel<<<dim3(8, M / 32), 256, 0, stream>>>(ctx, WoT, bo, proj);
  // 4. out = LN(x + proj)
  residual_ln_kernel<<<M / 2, 256, 0, stream>>>(x, proj, gamma, beta, out);
}

// Round 17
// 59.176 us; speedup vs baseline: 1.3706x; 1.3706x over previous
//
#include <hip/hip_runtime.h>
#include <hip/hip_bf16.h>
#include <math.h>

#define B 4
#define L 512
#define H 512
#define NH 8
#define DK 64
#define RIN 53
#define RHID 32

using short8 = __attribute__((ext_vector_type(8))) short;
using ushort8v = __attribute__((ext_vector_type(8))) unsigned short;
using f32x4 = __attribute__((ext_vector_type(4))) float;

__device__ __forceinline__ unsigned short cvt_bf16(float f) {
  __hip_bfloat16 h = __float2bfloat16(f);  // RNE; compiler emits cvt_pk pairs
  return __builtin_bit_cast(unsigned short, h);
}
__device__ __forceinline__ float bf2f(unsigned short u) {
  return __uint_as_float((unsigned)u << 16);
}

// ---------------------------------------------------------------------------
// prep: blocks 0..3 = per-batch mask compaction; blocks 4..131 = W transposes
// ---------------------------------------------------------------------------
__global__ __launch_bounds__(512) void prep_kernel(
    const int* __restrict__ mask, int* __restrict__ jidx, int* __restrict__ nv,
    const float* __restrict__ Wv, const float* __restrict__ Wo,
    unsigned short* __restrict__ WvT, unsigned short* __restrict__ WoT) {
  const int bid = blockIdx.x;
  const int tid = threadIdx.x;
  if (bid < 4) {
    const int b = bid;
    const int lane = tid & 63, wv = tid >> 6;
    __shared__ int wtot[8], woff[8];
    const int m = (mask[b * 512 + tid] != 0);
    const unsigned long long bal = __ballot(m);
    const int lpre = __popcll(bal & ((1ull << lane) - 1ull));
    if (lane == 0) wtot[wv] = __popcll(bal);
    __syncthreads();
    if (tid == 0) {
      int acc = 0;
#pragma unroll
      for (int q = 0; q < 8; ++q) {
        woff[q] = acc;
        acc += wtot[q];
      }
      nv[b] = acc;
    }
    __syncthreads();
    if (m) jidx[b * 512 + woff[wv] + lpre] = tid;
    return;
  }
  const int t = bid - 4;      // 0..127
  const int matsel = t >> 6;  // 0 = Wv, 1 = Wo
  const int tile = t & 63;
  const float* W = matsel ? Wo : Wv;
  unsigned short* WT = matsel ? WoT : WvT;
  const int k0 = (tile & 7) * 64, n0 = (tile >> 3) * 64;
  __shared__ float sT[64][65];
  {
    const int r = tid >> 3, c0 = (tid & 7) * 8;
    const float4 v0 = *(const float4*)(W + (size_t)(k0 + r) * 512 + n0 + c0);
    const float4 v1 = *(const float4*)(W + (size_t)(k0 + r) * 512 + n0 + c0 + 4);
    sT[r][c0] = v0.x; sT[r][c0 + 1] = v0.y; sT[r][c0 + 2] = v0.z; sT[r][c0 + 3] = v0.w;
    sT[r][c0 + 4] = v1.x; sT[r][c0 + 5] = v1.y; sT[r][c0 + 6] = v1.z; sT[r][c0 + 7] = v1.w;
  }
  __syncthreads();
  {
    const int n = tid >> 3, c0 = (tid & 7) * 8;
    ushort8v o;
#pragma unroll
    for (int cc = 0; cc < 8; ++cc) o[cc] = cvt_bf16(sT[c0 + cc][n]);
    *(ushort8v*)(WT + (size_t)(n0 + n) * 512 + k0 + c0) = o;
  }
}

// ---------------------------------------------------------------------------
// bf16 MFMA GEMM core: C[32 m x 64 n], K=512, templated BK (64 or 128),
// 256 thr.  smem: sA (32 x (BK+8)), sB (64 x (BK+8)); sC f32[32][68]
// aliases @0 (safe: all sA/sB reads complete at the final in-loop barrier).
// NOTE (R8/R11/R14/R16 lessons): GEMM phases need >=256 blocks; many small
// 256-thr blocks with cheap barriers beat fewer wide blocks; and never add
// extra code paths to a fused kernel — every path pays the worst path's
// register bill.
// ---------------------------------------------------------------------------
template <int AMODE, int OMODE, int BK>
__device__ __forceinline__ void gemm32x64(
    char* __restrict__ smem, const void* __restrict__ Aq, int lda,
    const unsigned short* __restrict__ Bs, int ldb,
    const float* __restrict__ bias, void* __restrict__ Cp, int ldc) {
  constexpr int KS = BK / 8;   // ushort8 slots per row
  constexpr int STR = BK + 8;  // padded row stride (shorts)
  constexpr int NA = 32 * KS / 256;
  constexpr int NB = 64 * KS / 256;
  unsigned short* sA = (unsigned short*)smem;
  unsigned short* sB = (unsigned short*)(smem + 32 * STR * 2);
  float(*sC)[68] = (float(*)[68])smem;
  const int tid = threadIdx.x;
  const int w = tid >> 6, l = tid & 63, g = l >> 4, a = l & 15;
  const int wm = (w >> 1) * 16, wn = (w & 1) * 32;
  f32x4 acc0 = {}, acc1 = {};

  ushort8v aR[NA], bR[NB];
  auto loadA = [&](int k0) {
#pragma unroll
    for (int q = 0; q < NA; ++q) {
      const int s = tid + q * 256;
      const int row = s / KS, kk = s % KS;
      if constexpr (AMODE == 1) {
        const float* Af = (const float*)Aq;
        const float* p = Af + (size_t)row * lda + k0 + kk * 8;
        const float4 v0 = *(const float4*)p;
        const float4 v1 = *(const float4*)(p + 4);
        ushort8v r;
        r[0] = cvt_bf16(v0.x); r[1] = cvt_bf16(v0.y);
        r[2] = cvt_bf16(v0.z); r[3] = cvt_bf16(v0.w);
        r[4] = cvt_bf16(v1.x); r[5] = cvt_bf16(v1.y);
        r[6] = cvt_bf16(v1.z); r[7] = cvt_bf16(v1.w);
        aR[q] = r;
      } else {
        const unsigned short* Ab = (const unsigned short*)Aq;
        aR[q] = *(const ushort8v*)(Ab + (size_t)row * lda + k0 + kk * 8);
      }
    }
  };
  auto loadB = [&](int k0) {
#pragma unroll
    for (int q = 0; q < NB; ++q) {
      const int s = tid + q * 256;
      const int row = s / KS, kk = s % KS;
      bR[q] = *(const ushort8v*)(Bs + (size_t)row * ldb + k0 + kk * 8);
    }
  };
  auto stage = [&]() {
#pragma unroll
    for (int q = 0; q < NA; ++q) {
      const int s = tid + q * 256;
      *(ushort8v*)(&sA[(s / KS) * STR + (s % KS) * 8]) = aR[q];
    }
#pragma unroll
    for (int q = 0; q < NB; ++q) {
      const int s = tid + q * 256;
      *(ushort8v*)(&sB[(s / KS) * STR + (s % KS) * 8]) = bR[q];
    }
  };

  loadA(0);
  loadB(0);
  for (int k0 = 0; k0 < 512; k0 += BK) {
    stage();
    __syncthreads();
    if (k0 + BK < 512) {
      loadA(k0 + BK);
      loadB(k0 + BK);
    }
#pragma unroll
    for (int ks = 0; ks < BK / 32; ++ks) {
      const short8 af = *(const short8*)(&sA[(wm + a) * STR + ks * 32 + g * 8]);
      const short8 bf0 = *(const short8*)(&sB[(wn + a) * STR + ks * 32 + g * 8]);
      const short8 bf1 =
          *(const short8*)(&sB[(wn + 16 + a) * STR + ks * 32 + g * 8]);
      acc0 = __builtin_amdgcn_mfma_f32_16x16x32_bf16(af, bf0, acc0, 0, 0, 0);
      acc1 = __builtin_amdgcn_mfma_f32_16x16x32_bf16(af, bf1, acc1, 0, 0, 0);
    }
    __syncthreads();
  }

#pragma unroll
  for (int r = 0; r < 4; ++r) {
    sC[wm + g * 4 + r][wn + a] = acc0[r];
    sC[wm + g * 4 + r][wn + 16 + a] = acc1[r];
  }
  __syncthreads();

  if constexpr (OMODE == 2) {
    const int n = tid >> 2, iq = (tid & 3) * 8;
    const float bv = bias ? bias[n] : 0.f;
    ushort8v o;
#pragma unroll
    for (int cc = 0; cc < 8; ++cc) o[cc] = cvt_bf16(sC[iq + cc][n] + bv);
    *(ushort8v*)((unsigned short*)Cp + (size_t)n * ldc + iq) = o;
  } else {
    const int m = tid >> 3, c8 = (tid & 7) * 8;
    float v[8];
#pragma unroll
    for (int cc = 0; cc < 8; ++cc) {
      v[cc] = sC[m][c8 + cc];
      if (bias) v[cc] += bias[c8 + cc];
    }
    if constexpr (OMODE == 1) {
      ushort8v o;
#pragma unroll
      for (int cc = 0; cc < 8; ++cc) o[cc] = cvt_bf16(v[cc]);
      *(ushort8v*)((unsigned short*)Cp + (size_t)m * ldc + c8) = o;
    } else {
      *(float4*)((float*)Cp + (size_t)m * ldc + c8) =
          make_float4(v[0], v[1], v[2], v[3]);
      *(float4*)((float*)Cp + (size_t)m * ldc + c8 + 4) =
          make_float4(v[4], v[5], v[6], v[7]);
    }
  }
}

#define GEMM64_SMEM 13824   // 32*72*2 + 64*72*2
#define GEMM128_SMEM 26112  // 32*136*2 + 64*136*2

// ---------------------------------------------------------------------------
// Fused launch: blocks 0..2047 = scores, blocks 2048..2559 = valT GEMM (BK64).
// ---------------------------------------------------------------------------
#define FUSED_SMEM 15616
__global__ __launch_bounds__(256) void fused_scores_value_kernel(
    const float* __restrict__ refCov, const int* __restrict__ mask,
    const int* __restrict__ jidx, const int* __restrict__ nvArr,
    const float* __restrict__ W1, const float* __restrict__ b1,
    const float* __restrict__ W2, const float* __restrict__ b2,
    unsigned short* __restrict__ attnb, const float* __restrict__ x,
    const unsigned short* __restrict__ WvT, const float* __restrict__ bv,
    unsigned short* __restrict__ valT) {
  __shared__ __align__(16) char smem[FUSED_SMEM];
  const int tid = threadIdx.x;

  if (blockIdx.x >= 2048) {
    const int gb = blockIdx.x - 2048;  // 0..511
    const int n0 = (gb & 7) * 64;
    const int m0 = (gb >> 3) * 32;
    const int b = m0 >> 9, i0 = m0 & 511;
    gemm32x64<1, 2, 64>(smem, x + (size_t)m0 * 512, 512,
                        WvT + (size_t)n0 * 512, 512, bv + n0,
                        valT + (size_t)b * 262144 + (size_t)n0 * 512 + i0, 512);
    return;
  }

  // ---- scores path ----
  unsigned short* sH1 = (unsigned short*)smem;            // [4][16][40]
  int* sJ = (int*)(smem + 5120);                          // [512]
  unsigned short* sOut = (unsigned short*)(smem + 7168);  // [8][512]
  float(*redbuf)[16] = (float(*)[16])(smem + 15360);      // [4][16]

  const int b = blockIdx.x >> 9;
  const int i = blockIdx.x & (L - 1);
  const int w = tid >> 6;
  const int l = tid & 63;
  const int g = l >> 4;
  const int a = l & 15;

  const int mi = mask[b * L + i];
  const int nv = nvArr[b];

  if (mi == 0 || nv == 0) {
    const ushort4 u4 = {0x3B00u, 0x3B00u, 0x3B00u, 0x3B00u};  // 1/512 bf16
#pragma unroll
    for (int q = 0; q < 4; ++q) {
      const int f4 = q * 256 + tid;
      const int h = f4 >> 7;
      const int c4 = f4 & 127;
      *(ushort4*)(attnb + ((size_t)(b * NH + h) * L + i) * L + c4 * 4) = u4;
    }
    return;
  }

  sJ[tid] = jidx[b * 512 + tid];
  sJ[tid + 256] = jidx[b * 512 + 256 + tid];

  short8 w1f[2][2];
#pragma unroll
  for (int ks = 0; ks < 2; ++ks)
#pragma unroll
    for (int nt = 0; nt < 2; ++nt)
#pragma unroll
      for (int e = 0; e < 8; ++e) {
        const int k = ks * 32 + g * 8 + e;
        w1f[ks][nt][e] =
            (k < RIN) ? (short)cvt_bf16(W1[k * RHID + nt * 16 + a]) : (short)0;
      }
  short8 w2f;
#pragma unroll
  for (int e = 0; e < 8; ++e) {
    const int k = g * 8 + e;
    w2f[e] = (a < NH) ? (short)cvt_bf16(W2[k * NH + a]) : (short)0;
  }
  const float b1v0 = b1[a];
  const float b1v1 = b1[16 + a];
  const float b2v = (a < NH) ? b2[a] : 0.f;

  __syncthreads();  // sJ ready

  const int NT = (nv + 15) >> 4;  // <= 32
  f32x4 sc[8];

#pragma unroll
  for (int mt = 0; mt < 8; ++mt) {
    const int t = mt * 4 + w;
    if (t >= NT) continue;
    const int s = t * 16 + a;
    const int j = sJ[(s < nv) ? s : (nv - 1)];
    const float* rp = refCov + ((size_t)((b << 9) + i) * 512 + j) * RIN;

    const float4 u0 = *(const float4*)(rp + g * 8);
    const float4 u1 = *(const float4*)(rp + g * 8 + 4);
    const int base0 = (g < 3) ? (32 + g * 8) : 32;
    const int base1 = (g == 0) ? 36 : (g == 1) ? 44 : 49;
    const float4 v0 = *(const float4*)(rp + base0);
    const float4 v1 = *(const float4*)(rp + base1);
    float t1[8];
    if (g < 3) {
      t1[0] = v0.x; t1[1] = v0.y; t1[2] = v0.z; t1[3] = v0.w;
    } else {
      t1[0] = 0.f; t1[1] = 0.f; t1[2] = 0.f; t1[3] = 0.f;
    }
    if (g < 2) {
      t1[4] = v1.x; t1[5] = v1.y; t1[6] = v1.z; t1[7] = v1.w;
    } else if (g == 2) {
      t1[4] = v1.w;  // k = 52
      t1[5] = 0.f; t1[6] = 0.f; t1[7] = 0.f;
    } else {
      t1[4] = 0.f; t1[5] = 0.f; t1[6] = 0.f; t1[7] = 0.f;
    }
    short8 af0, af1;
    af0[0] = (short)cvt_bf16(u0.x); af0[1] = (short)cvt_bf16(u0.y);
    af0[2] = (short)cvt_bf16(u0.z); af0[3] = (short)cvt_bf16(u0.w);
    af0[4] = (short)cvt_bf16(u1.x); af0[5] = (short)cvt_bf16(u1.y);
    af0[6] = (short)cvt_bf16(u1.z); af0[7] = (short)cvt_bf16(u1.w);
#pragma unroll
    for (int e = 0; e < 8; ++e) af1[e] = (short)cvt_bf16(t1[e]);

    f32x4 h0 = f32x4{b1v0, b1v0, b1v0, b1v0};
    f32x4 h1v = f32x4{b1v1, b1v1, b1v1, b1v1};
    h0 = __builtin_amdgcn_mfma_f32_16x16x32_bf16(af0, w1f[0][0], h0, 0, 0, 0);
    h1v = __builtin_amdgcn_mfma_f32_16x16x32_bf16(af0, w1f[0][1], h1v, 0, 0, 0);
    h0 = __builtin_amdgcn_mfma_f32_16x16x32_bf16(af1, w1f[1][0], h0, 0, 0, 0);
    h1v = __builtin_amdgcn_mfma_f32_16x16x32_bf16(af1, w1f[1][1], h1v, 0, 0, 0);

#pragma unroll
    for (int r = 0; r < 4; ++r) {
      sH1[(w * 16 + g * 4 + r) * 40 + a] = cvt_bf16(fmaxf(h0[r], 0.f));
      sH1[(w * 16 + g * 4 + r) * 40 + 16 + a] = cvt_bf16(fmaxf(h1v[r], 0.f));
    }

    const short8 af2 = *(const short8*)(&sH1[(w * 16 + a) * 40 + g * 8]);
    f32x4 acc = f32x4{b2v, b2v, b2v, b2v};
    sc[mt] = __builtin_amdgcn_mfma_f32_16x16x32_bf16(af2, w2f, acc, 0, 0, 0);
  }

  float mx = -INFINITY;
#pragma unroll
  for (int mt = 0; mt < 8; ++mt) {
    const int t = mt * 4 + w;
    if (t >= NT) continue;
#pragma unroll
    for (int r = 0; r < 4; ++r) {
      const int s = t * 16 + g * 4 + r;
      if (s < nv) mx = fmaxf(mx, sc[mt][r]);
    }
  }
  mx = fmaxf(mx, __shfl_xor(mx, 16, 64));
  mx = fmaxf(mx, __shfl_xor(mx, 32, 64));
  if (g == 0) redbuf[w][a] = mx;
  __syncthreads();
  const float rmax = fmaxf(fmaxf(redbuf[0][a], redbuf[1][a]),
                           fmaxf(redbuf[2][a], redbuf[3][a]));
  __syncthreads();

  float lsum = 0.f;
#pragma unroll
  for (int mt = 0; mt < 8; ++mt) {
    const int t = mt * 4 + w;
    if (t >= NT) continue;
#pragma unroll
    for (int r = 0; r < 4; ++r) {
      const int s = t * 16 + g * 4 + r;
      const float e = (s < nv) ? __expf(sc[mt][r] - rmax) : 0.f;
      sc[mt][r] = e;
      lsum += e;
    }
  }
  lsum += __shfl_xor(lsum, 16, 64);
  lsum += __shfl_xor(lsum, 32, 64);
  if (g == 0) redbuf[w][a] = lsum;
  __syncthreads();
  const float rsum = redbuf[0][a] + redbuf[1][a] + redbuf[2][a] + redbuf[3][a];
  const float inv = 1.f / rsum;

  {
    const ushort8v z{};
    *(ushort8v*)(&sOut[tid * 16]) = z;
    *(ushort8v*)(&sOut[tid * 16 + 8]) = z;
  }
  __syncthreads();
  if (a < NH) {
#pragma unroll
    for (int mt = 0; mt < 8; ++mt) {
      const int t = mt * 4 + w;
      if (t >= NT) continue;
#pragma unroll
      for (int r = 0; r < 4; ++r) {
        const int s = t * 16 + g * 4 + r;
        if (s < nv) sOut[a * 512 + sJ[s]] = cvt_bf16(sc[mt][r] * inv);
      }
    }
  }
  __syncthreads();
  {
    const int h = tid >> 5, off = (tid & 31) * 16;
    unsigned short* dst = attnb + ((size_t)(b * NH + h) * L + i) * L + off;
    *(ushort8v*)dst = *(const ushort8v*)(&sOut[h * 512 + off]);
    *(ushort8v*)(dst + 8) = *(const ushort8v*)(&sOut[h * 512 + off + 8]);
  }
}

// ctx[b,i,h*64+d] = sum_j attn[b,h,i,j] * valT[b][h*64+d][j]  (BK=128)
__global__ __launch_bounds__(256) void attn_value_kernel(
    const unsigned short* __restrict__ attnb,
    const unsigned short* __restrict__ valT, unsigned short* __restrict__ ctx) {
  __shared__ __align__(16) char smem[GEMM128_SMEM];
  const int bid = blockIdx.x;  // it(16) x h(8) x b(4)
  const int it = bid & 15, h = (bid >> 4) & 7, b = bid >> 7;
  const int i0 = it * 32;
  gemm32x64<0, 1, 128>(smem, attnb + ((size_t)((b * 8 + h) * 512 + i0)) * 512,
                       512, valT + (size_t)b * 262144 + (size_t)(h * 64) * 512,
                       512, nullptr,
                       ctx + ((size_t)(b * 512 + i0)) * 512 + h * 64, 512);
}

// proj = ctx @ WoT + bo  (bf16 out, BK=128), grid (8, 64)
__global__ __launch_bounds__(256) void gemm_proj_kernel(
    const unsigned short* __restrict__ ctx,
    const unsigned short* __restrict__ WoT, const float* __restrict__ bo,
    unsigned short* __restrict__ proj) {
  __shared__ __align__(16) char smem[GEMM128_SMEM];
  const int n0 = blockIdx.x * 64;
  const int m0 = blockIdx.y * 32;
  gemm32x64<0, 1, 128>(smem, ctx + (size_t)m0 * 512, 512,
                       WoT + (size_t)n0 * 512, 512, bo + n0,
                       proj + (size_t)m0 * 512 + n0, 512);
}

// ---------------------------------------------------------------------------
// out = LN(x + proj) * gamma + beta.  2 rows per 256-thr block (grid 1024),
// float4 x / ushort4 proj loads, float4 stores.
// ---------------------------------------------------------------------------
__global__ __launch_bounds__(256) void residual_ln_kernel(
    const float* __restrict__ x, const unsigned short* __restrict__ proj,
    const float* __restrict__ gamma, const float* __restrict__ beta,
    float* __restrict__ out) {
  const int tid = threadIdx.x;
  const int rh = tid >> 7;  // row half (0/1)
  const int q = tid & 127;  // float4 index within row
  const int row = blockIdx.x * 2 + rh;
  __shared__ float redS[4], redQ[4];

  const float4 xv = *(const float4*)(x + (size_t)row * H + q * 4);
  const ushort4 pv = *(const ushort4*)(proj + (size_t)row * H + q * 4);
  float y[4] = {xv.x + bf2f(pv.x), xv.y + bf2f(pv.y), xv.z + bf2f(pv.z),
                xv.w + bf2f(pv.w)};
  float ls = y[0] + y[1] + y[2] + y[3];
  float lq = y[0] * y[0] + y[1] * y[1] + y[2] * y[2] + y[3] * y[3];
#pragma unroll
  for (int off = 32; off > 0; off >>= 1) {
    ls += __shfl_xor(ls, off, 64);
    lq += __shfl_xor(lq, off, 64);
  }
  const int wave = tid >> 6, lane = tid & 63;
  if (lane == 0) {
    redS[wave] = ls;
    redQ[wave] = lq;
  }
  __syncthreads();
  const float sum = redS[rh * 2] + redS[rh * 2 + 1];
  const float sq = redQ[rh * 2] + redQ[rh * 2 + 1];
  const float mu = sum * (1.f / H);
  const float var = sq * (1.f / H) - mu * mu;
  const float inv = rsqrtf(var + 1e-5f);
  const float4 gm = *(const float4*)(gamma + q * 4);
  const float4 bt = *(const float4*)(beta + q * 4);
  float4 o;
  o.x = (y[0] - mu) * inv * gm.x + bt.x;
  o.y = (y[1] - mu) * inv * gm.y + bt.y;
  o.z = (y[2] - mu) * inv * gm.z + bt.z;
  o.w = (y[3] - mu) * inv * gm.w + bt.w;
  *(float4*)(out + (size_t)row * H + q * 4) = o;
}

extern "C" void kernel_launch(void* const* d_in, const int* in_sizes, int n_in,
                              void* d_out, int out_size, void* d_ws,
                              size_t ws_size, hipStream_t stream) {
  const float* x = (const float*)d_in[0];
  const int* mask = (const int*)d_in[1];
  const float* refCov = (const float*)d_in[2];
  const float* Wv = (const float*)d_in[3];
  const float* bv = (const float*)d_in[4];
  const float* W1 = (const float*)d_in[5];
  const float* b1 = (const float*)d_in[6];
  const float* W2 = (const float*)d_in[7];
  const float* b2 = (const float*)d_in[8];
  const float* Wo = (const float*)d_in[9];
  const float* bo = (const float*)d_in[10];
  const float* gamma = (const float*)d_in[11];
  const float* beta = (const float*)d_in[12];
  float* out = (float*)d_out;

  const size_t n_attn = (size_t)B * NH * L * L;  // 8388608 (bf16)
  const size_t n_blh = (size_t)B * L * H;        // 1048576
  const size_t n_w = (size_t)H * H;              // 262144
  unsigned short* attnb = (unsigned short*)d_ws;
  unsigned short* valT = attnb + n_attn;
  unsigned short* ctx = valT + n_blh;
  unsigned short* WvT = ctx + n_blh;
  unsigned short* WoT = WvT + n_w;
  unsigned short* proj = WoT + n_w;  // bf16
  int* jidx = (int*)(proj + n_blh);
  int* nv = jidx + B * L;
  const size_t needed =
      (n_attn + 3 * n_blh + 2 * n_w) * 2 + (B * L + B) * 4;
  if (ws_size < needed) return;

  const int M = B * L;  // 2048

  // 0. compaction + W transposes
  prep_kernel<<<132, 512, 0, stream>>>(mask, jidx, nv, Wv, Wo, WvT, WoT);
  // 1. scores + valT GEMM in one heterogeneous launch
  fused_scores_value_kernel<<<2048 + 512, 256, 0, stream>>>(
      refCov, mask, jidx, nv, W1, b1, W2, b2, attnb, x, WvT, bv, valT);
  // 2. ctx = attn @ value  (BK=128)
  attn_value_kernel<<<512, 256, 0, stream>>>(attnb, valT, ctx);
  // 3. proj = ctx @ WoT + bo  (bf16, BK=128, 512 blocks)
  gemm_proj_kernel<<<dim3(8, M / 32), 256, 0, stream>>>(ctx, WoT, bo, proj);
  // 4. out = LN(x + proj)
  residual_ln_kernel<<<M / 2, 256, 0, stream>>>(x, proj, gamma, beta, out);
}

// Round 18
// 56.918 us; speedup vs baseline: 1.4249x; 1.0397x over previous
//
#include <hip/hip_runtime.h>
#include <hip/hip_bf16.h>
#include <math.h>

#define B 4
#define L 512
#define H 512
#define NH 8
#define DK 64
#define RIN 53
#define RHID 32

using short8 = __attribute__((ext_vector_type(8))) short;
using ushort8v = __attribute__((ext_vector_type(8))) unsigned short;
using f32x4 = __attribute__((ext_vector_type(4))) float;

__device__ __forceinline__ unsigned short cvt_bf16(float f) {
  __hip_bfloat16 h = __float2bfloat16(f);  // RNE; compiler emits cvt_pk pairs
  return __builtin_bit_cast(unsigned short, h);
}
__device__ __forceinline__ float bf2f(unsigned short u) {
  return __uint_as_float((unsigned)u << 16);
}

// ---------------------------------------------------------------------------
// prep: blocks 0..3 = per-batch mask compaction; blocks 4..131 = W transposes
// ---------------------------------------------------------------------------
__global__ __launch_bounds__(512) void prep_kernel(
    const int* __restrict__ mask, int* __restrict__ jidx, int* __restrict__ nv,
    const float* __restrict__ Wv, const float* __restrict__ Wo,
    unsigned short* __restrict__ WvT, unsigned short* __restrict__ WoT) {
  const int bid = blockIdx.x;
  const int tid = threadIdx.x;
  if (bid < 4) {
    const int b = bid;
    const int lane = tid & 63, wv = tid >> 6;
    __shared__ int wtot[8], woff[8];
    const int m = (mask[b * 512 + tid] != 0);
    const unsigned long long bal = __ballot(m);
    const int lpre = __popcll(bal & ((1ull << lane) - 1ull));
    if (lane == 0) wtot[wv] = __popcll(bal);
    __syncthreads();
    if (tid == 0) {
      int acc = 0;
#pragma unroll
      for (int q = 0; q < 8; ++q) {
        woff[q] = acc;
        acc += wtot[q];
      }
      nv[b] = acc;
    }
    __syncthreads();
    if (m) jidx[b * 512 + woff[wv] + lpre] = tid;
    return;
  }
  const int t = bid - 4;      // 0..127
  const int matsel = t >> 6;  // 0 = Wv, 1 = Wo
  const int tile = t & 63;
  const float* W = matsel ? Wo : Wv;
  unsigned short* WT = matsel ? WoT : WvT;
  const int k0 = (tile & 7) * 64, n0 = (tile >> 3) * 64;
  __shared__ float sT[64][65];
  {
    const int r = tid >> 3, c0 = (tid & 7) * 8;
    const float4 v0 = *(const float4*)(W + (size_t)(k0 + r) * 512 + n0 + c0);
    const float4 v1 = *(const float4*)(W + (size_t)(k0 + r) * 512 + n0 + c0 + 4);
    sT[r][c0] = v0.x; sT[r][c0 + 1] = v0.y; sT[r][c0 + 2] = v0.z; sT[r][c0 + 3] = v0.w;
    sT[r][c0 + 4] = v1.x; sT[r][c0 + 5] = v1.y; sT[r][c0 + 6] = v1.z; sT[r][c0 + 7] = v1.w;
  }
  __syncthreads();
  {
    const int n = tid >> 3, c0 = (tid & 7) * 8;
    ushort8v o;
#pragma unroll
    for (int cc = 0; cc < 8; ++cc) o[cc] = cvt_bf16(sT[c0 + cc][n]);
    *(ushort8v*)(WT + (size_t)(n0 + n) * 512 + k0 + c0) = o;
  }
}

// ---------------------------------------------------------------------------
// bf16 MFMA GEMM core: C[32 m x 64 n], K=512, templated BK (64 or 128),
// 256 thr.  smem: sA (32 x (BK+8)), sB (64 x (BK+8)); sC f32[32][68]
// aliases @0 (safe: all sA/sB reads complete at the final in-loop barrier).
// NOTE (R8/R11/R14/R16 lessons): GEMM phases need >=256 blocks; many small
// 256-thr blocks with cheap barriers beat fewer wide blocks; never add
// extra code paths to a fused kernel — every path pays the worst path's
// register bill.
// ---------------------------------------------------------------------------
template <int AMODE, int OMODE, int BK>
__device__ __forceinline__ void gemm32x64(
    char* __restrict__ smem, const void* __restrict__ Aq, int lda,
    const unsigned short* __restrict__ Bs, int ldb,
    const float* __restrict__ bias, void* __restrict__ Cp, int ldc) {
  constexpr int KS = BK / 8;   // ushort8 slots per row
  constexpr int STR = BK + 8;  // padded row stride (shorts)
  constexpr int NA = 32 * KS / 256;
  constexpr int NB = 64 * KS / 256;
  unsigned short* sA = (unsigned short*)smem;
  unsigned short* sB = (unsigned short*)(smem + 32 * STR * 2);
  float(*sC)[68] = (float(*)[68])smem;
  const int tid = threadIdx.x;
  const int w = tid >> 6, l = tid & 63, g = l >> 4, a = l & 15;
  const int wm = (w >> 1) * 16, wn = (w & 1) * 32;
  f32x4 acc0 = {}, acc1 = {};

  ushort8v aR[NA], bR[NB];
  auto loadA = [&](int k0) {
#pragma unroll
    for (int q = 0; q < NA; ++q) {
      const int s = tid + q * 256;
      const int row = s / KS, kk = s % KS;
      if constexpr (AMODE == 1) {
        const float* Af = (const float*)Aq;
        const float* p = Af + (size_t)row * lda + k0 + kk * 8;
        const float4 v0 = *(const float4*)p;
        const float4 v1 = *(const float4*)(p + 4);
        ushort8v r;
        r[0] = cvt_bf16(v0.x); r[1] = cvt_bf16(v0.y);
        r[2] = cvt_bf16(v0.z); r[3] = cvt_bf16(v0.w);
        r[4] = cvt_bf16(v1.x); r[5] = cvt_bf16(v1.y);
        r[6] = cvt_bf16(v1.z); r[7] = cvt_bf16(v1.w);
        aR[q] = r;
      } else {
        const unsigned short* Ab = (const unsigned short*)Aq;
        aR[q] = *(const ushort8v*)(Ab + (size_t)row * lda + k0 + kk * 8);
      }
    }
  };
  auto loadB = [&](int k0) {
#pragma unroll
    for (int q = 0; q < NB; ++q) {
      const int s = tid + q * 256;
      const int row = s / KS, kk = s % KS;
      bR[q] = *(const ushort8v*)(Bs + (size_t)row * ldb + k0 + kk * 8);
    }
  };
  auto stage = [&]() {
#pragma unroll
    for (int q = 0; q < NA; ++q) {
      const int s = tid + q * 256;
      *(ushort8v*)(&sA[(s / KS) * STR + (s % KS) * 8]) = aR[q];
    }
#pragma unroll
    for (int q = 0; q < NB; ++q) {
      const int s = tid + q * 256;
      *(ushort8v*)(&sB[(s / KS) * STR + (s % KS) * 8]) = bR[q];
    }
  };

  loadA(0);
  loadB(0);
  for (int k0 = 0; k0 < 512; k0 += BK) {
    stage();
    __syncthreads();
    if (k0 + BK < 512) {
      loadA(k0 + BK);
      loadB(k0 + BK);
    }
#pragma unroll
    for (int ks = 0; ks < BK / 32; ++ks) {
      const short8 af = *(const short8*)(&sA[(wm + a) * STR + ks * 32 + g * 8]);
      const short8 bf0 = *(const short8*)(&sB[(wn + a) * STR + ks * 32 + g * 8]);
      const short8 bf1 =
          *(const short8*)(&sB[(wn + 16 + a) * STR + ks * 32 + g * 8]);
      acc0 = __builtin_amdgcn_mfma_f32_16x16x32_bf16(af, bf0, acc0, 0, 0, 0);
      acc1 = __builtin_amdgcn_mfma_f32_16x16x32_bf16(af, bf1, acc1, 0, 0, 0);
    }
    __syncthreads();
  }

#pragma unroll
  for (int r = 0; r < 4; ++r) {
    sC[wm + g * 4 + r][wn + a] = acc0[r];
    sC[wm + g * 4 + r][wn + 16 + a] = acc1[r];
  }
  __syncthreads();

  if constexpr (OMODE == 2) {
    const int n = tid >> 2, iq = (tid & 3) * 8;
    const float bv = bias ? bias[n] : 0.f;
    ushort8v o;
#pragma unroll
    for (int cc = 0; cc < 8; ++cc) o[cc] = cvt_bf16(sC[iq + cc][n] + bv);
    *(ushort8v*)((unsigned short*)Cp + (size_t)n * ldc + iq) = o;
  } else {
    const int m = tid >> 3, c8 = (tid & 7) * 8;
    float v[8];
#pragma unroll
    for (int cc = 0; cc < 8; ++cc) {
      v[cc] = sC[m][c8 + cc];
      if (bias) v[cc] += bias[c8 + cc];
    }
    if constexpr (OMODE == 1) {
      ushort8v o;
#pragma unroll
      for (int cc = 0; cc < 8; ++cc) o[cc] = cvt_bf16(v[cc]);
      *(ushort8v*)((unsigned short*)Cp + (size_t)m * ldc + c8) = o;
    } else {
      *(float4*)((float*)Cp + (size_t)m * ldc + c8) =
          make_float4(v[0], v[1], v[2], v[3]);
      *(float4*)((float*)Cp + (size_t)m * ldc + c8 + 4) =
          make_float4(v[4], v[5], v[6], v[7]);
    }
  }
}

#define GEMM64_SMEM 13824   // 32*72*2 + 64*72*2
#define GEMM128_SMEM 26112  // 32*136*2 + 64*136*2

// ---------------------------------------------------------------------------
// Fused launch: blocks 0..511 = valT GEMM (BK64, dispatched FIRST so the
// producer for attn_value completes while scores still runs);
// blocks 512..2559 = scores.
// ---------------------------------------------------------------------------
#define FUSED_SMEM 15616
__global__ __launch_bounds__(256) void fused_scores_value_kernel(
    const float* __restrict__ refCov, const int* __restrict__ mask,
    const int* __restrict__ jidx, const int* __restrict__ nvArr,
    const float* __restrict__ W1, const float* __restrict__ b1,
    const float* __restrict__ W2, const float* __restrict__ b2,
    unsigned short* __restrict__ attnb, const float* __restrict__ x,
    const unsigned short* __restrict__ WvT, const float* __restrict__ bv,
    unsigned short* __restrict__ valT) {
  __shared__ __align__(16) char smem[FUSED_SMEM];
  const int tid = threadIdx.x;

  if (blockIdx.x < 512) {
    const int gb = blockIdx.x;  // 0..511
    const int n0 = (gb & 7) * 64;
    const int m0 = (gb >> 3) * 32;
    const int b = m0 >> 9, i0 = m0 & 511;
    gemm32x64<1, 2, 64>(smem, x + (size_t)m0 * 512, 512,
                        WvT + (size_t)n0 * 512, 512, bv + n0,
                        valT + (size_t)b * 262144 + (size_t)n0 * 512 + i0, 512);
    return;
  }

  // ---- scores path ----
  unsigned short* sH1 = (unsigned short*)smem;            // [4][16][40]
  int* sJ = (int*)(smem + 5120);                          // [512]
  unsigned short* sOut = (unsigned short*)(smem + 7168);  // [8][512]
  float(*redbuf)[16] = (float(*)[16])(smem + 15360);      // [4][16]

  const int sbid = blockIdx.x - 512;  // 0..2047
  const int b = sbid >> 9;
  const int i = sbid & (L - 1);
  const int w = tid >> 6;
  const int l = tid & 63;
  const int g = l >> 4;
  const int a = l & 15;

  const int mi = mask[b * L + i];
  const int nv = nvArr[b];

  if (mi == 0 || nv == 0) {
    const ushort4 u4 = {0x3B00u, 0x3B00u, 0x3B00u, 0x3B00u};  // 1/512 bf16
#pragma unroll
    for (int q = 0; q < 4; ++q) {
      const int f4 = q * 256 + tid;
      const int h = f4 >> 7;
      const int c4 = f4 & 127;
      *(ushort4*)(attnb + ((size_t)(b * NH + h) * L + i) * L + c4 * 4) = u4;
    }
    return;
  }

  sJ[tid] = jidx[b * 512 + tid];
  sJ[tid + 256] = jidx[b * 512 + 256 + tid];

  short8 w1f[2][2];
#pragma unroll
  for (int ks = 0; ks < 2; ++ks)
#pragma unroll
    for (int nt = 0; nt < 2; ++nt)
#pragma unroll
      for (int e = 0; e < 8; ++e) {
        const int k = ks * 32 + g * 8 + e;
        w1f[ks][nt][e] =
            (k < RIN) ? (short)cvt_bf16(W1[k * RHID + nt * 16 + a]) : (short)0;
      }
  short8 w2f;
#pragma unroll
  for (int e = 0; e < 8; ++e) {
    const int k = g * 8 + e;
    w2f[e] = (a < NH) ? (short)cvt_bf16(W2[k * NH + a]) : (short)0;
  }
  const float b1v0 = b1[a];
  const float b1v1 = b1[16 + a];
  const float b2v = (a < NH) ? b2[a] : 0.f;

  __syncthreads();  // sJ ready

  const int NT = (nv + 15) >> 4;  // <= 32
  f32x4 sc[8];

#pragma unroll
  for (int mt = 0; mt < 8; ++mt) {
    const int t = mt * 4 + w;
    if (t >= NT) continue;
    const int s = t * 16 + a;
    const int j = sJ[(s < nv) ? s : (nv - 1)];
    const float* rp = refCov + ((size_t)((b << 9) + i) * 512 + j) * RIN;

    const float4 u0 = *(const float4*)(rp + g * 8);
    const float4 u1 = *(const float4*)(rp + g * 8 + 4);
    const int base0 = (g < 3) ? (32 + g * 8) : 32;
    const int base1 = (g == 0) ? 36 : (g == 1) ? 44 : 49;
    const float4 v0 = *(const float4*)(rp + base0);
    const float4 v1 = *(const float4*)(rp + base1);
    float t1[8];
    if (g < 3) {
      t1[0] = v0.x; t1[1] = v0.y; t1[2] = v0.z; t1[3] = v0.w;
    } else {
      t1[0] = 0.f; t1[1] = 0.f; t1[2] = 0.f; t1[3] = 0.f;
    }
    if (g < 2) {
      t1[4] = v1.x; t1[5] = v1.y; t1[6] = v1.z; t1[7] = v1.w;
    } else if (g == 2) {
      t1[4] = v1.w;  // k = 52
      t1[5] = 0.f; t1[6] = 0.f; t1[7] = 0.f;
    } else {
      t1[4] = 0.f; t1[5] = 0.f; t1[6] = 0.f; t1[7] = 0.f;
    }
    short8 af0, af1;
    af0[0] = (short)cvt_bf16(u0.x); af0[1] = (short)cvt_bf16(u0.y);
    af0[2] = (short)cvt_bf16(u0.z); af0[3] = (short)cvt_bf16(u0.w);
    af0[4] = (short)cvt_bf16(u1.x); af0[5] = (short)cvt_bf16(u1.y);
    af0[6] = (short)cvt_bf16(u1.z); af0[7] = (short)cvt_bf16(u1.w);
#pragma unroll
    for (int e = 0; e < 8; ++e) af1[e] = (short)cvt_bf16(t1[e]);

    f32x4 h0 = f32x4{b1v0, b1v0, b1v0, b1v0};
    f32x4 h1v = f32x4{b1v1, b1v1, b1v1, b1v1};
    h0 = __builtin_amdgcn_mfma_f32_16x16x32_bf16(af0, w1f[0][0], h0, 0, 0, 0);
    h1v = __builtin_amdgcn_mfma_f32_16x16x32_bf16(af0, w1f[0][1], h1v, 0, 0, 0);
    h0 = __builtin_amdgcn_mfma_f32_16x16x32_bf16(af1, w1f[1][0], h0, 0, 0, 0);
    h1v = __builtin_amdgcn_mfma_f32_16x16x32_bf16(af1, w1f[1][1], h1v, 0, 0, 0);

#pragma unroll
    for (int r = 0; r < 4; ++r) {
      sH1[(w * 16 + g * 4 + r) * 40 + a] = cvt_bf16(fmaxf(h0[r], 0.f));
      sH1[(w * 16 + g * 4 + r) * 40 + 16 + a] = cvt_bf16(fmaxf(h1v[r], 0.f));
    }

    const short8 af2 = *(const short8*)(&sH1[(w * 16 + a) * 40 + g * 8]);
    f32x4 acc = f32x4{b2v, b2v, b2v, b2v};
    sc[mt] = __builtin_amdgcn_mfma_f32_16x16x32_bf16(af2, w2f, acc, 0, 0, 0);
  }

  float mx = -INFINITY;
#pragma unroll
  for (int mt = 0; mt < 8; ++mt) {
    const int t = mt * 4 + w;
    if (t >= NT) continue;
#pragma unroll
    for (int r = 0; r < 4; ++r) {
      const int s = t * 16 + g * 4 + r;
      if (s < nv) mx = fmaxf(mx, sc[mt][r]);
    }
  }
  mx = fmaxf(mx, __shfl_xor(mx, 16, 64));
  mx = fmaxf(mx, __shfl_xor(mx, 32, 64));
  if (g == 0) redbuf[w][a] = mx;
  __syncthreads();
  const float rmax = fmaxf(fmaxf(redbuf[0][a], redbuf[1][a]),
                           fmaxf(redbuf[2][a], redbuf[3][a]));
  __syncthreads();

  float lsum = 0.f;
#pragma unroll
  for (int mt = 0; mt < 8; ++mt) {
    const int t = mt * 4 + w;
    if (t >= NT) continue;
#pragma unroll
    for (int r = 0; r < 4; ++r) {
      const int s = t * 16 + g * 4 + r;
      const float e = (s < nv) ? __expf(sc[mt][r] - rmax) : 0.f;
      sc[mt][r] = e;
      lsum += e;
    }
  }
  lsum += __shfl_xor(lsum, 16, 64);
  lsum += __shfl_xor(lsum, 32, 64);
  if (g == 0) redbuf[w][a] = lsum;
  __syncthreads();
  const float rsum = redbuf[0][a] + redbuf[1][a] + redbuf[2][a] + redbuf[3][a];
  const float inv = 1.f / rsum;

  {
    const ushort8v z{};
    *(ushort8v*)(&sOut[tid * 16]) = z;
    *(ushort8v*)(&sOut[tid * 16 + 8]) = z;
  }
  __syncthreads();
  if (a < NH) {
#pragma unroll
    for (int mt = 0; mt < 8; ++mt) {
      const int t = mt * 4 + w;
      if (t >= NT) continue;
#pragma unroll
      for (int r = 0; r < 4; ++r) {
        const int s = t * 16 + g * 4 + r;
        if (s < nv) sOut[a * 512 + sJ[s]] = cvt_bf16(sc[mt][r] * inv);
      }
    }
  }
  __syncthreads();
  {
    const int h = tid >> 5, off = (tid & 31) * 16;
    unsigned short* dst = attnb + ((size_t)(b * NH + h) * L + i) * L + off;
    *(ushort8v*)dst = *(const ushort8v*)(&sOut[h * 512 + off]);
    *(ushort8v*)(dst + 8) = *(const ushort8v*)(&sOut[h * 512 + off + 8]);
  }
}

// ctx[b,i,h*64+d] = sum_j attn[b,h,i,j] * valT[b][h*64+d][j]  (BK=128)
__global__ __launch_bounds__(256) void attn_value_kernel(
    const unsigned short* __restrict__ attnb,
    const unsigned short* __restrict__ valT, unsigned short* __restrict__ ctx) {
  __shared__ __align__(16) char smem[GEMM128_SMEM];
  const int bid = blockIdx.x;  // it(16) x h(8) x b(4)
  const int it = bid & 15, h = (bid >> 4) & 7, b = bid >> 7;
  const int i0 = it * 32;
  gemm32x64<0, 1, 128>(smem, attnb + ((size_t)((b * 8 + h) * 512 + i0)) * 512,
                       512, valT + (size_t)b * 262144 + (size_t)(h * 64) * 512,
                       512, nullptr,
                       ctx + ((size_t)(b * 512 + i0)) * 512 + h * 64, 512);
}

// proj = ctx @ WoT + bo  (bf16 out, BK=128), grid (8, 64)
__global__ __launch_bounds__(256) void gemm_proj_kernel(
    const unsigned short* __restrict__ ctx,
    const unsigned short* __restrict__ WoT, const float* __restrict__ bo,
    unsigned short* __restrict__ proj) {
  __shared__ __align__(16) char smem[GEMM128_SMEM];
  const int n0 = blockIdx.x * 64;
  const int m0 = blockIdx.y * 32;
  gemm32x64<0, 1, 128>(smem, ctx + (size_t)m0 * 512, 512,
                       WoT + (size_t)n0 * 512, 512, bo + n0,
                       proj + (size_t)m0 * 512 + n0, 512);
}

// ---------------------------------------------------------------------------
// out = LN(x + proj) * gamma + beta.  2 rows per 256-thr block (grid 1024),
// float4 x / ushort4 proj loads, float4 stores.
// ---------------------------------------------------------------------------
__global__ __launch_bounds__(256) void residual_ln_kernel(
    const float* __restrict__ x, const unsigned short* __restrict__ proj,
    const float* __restrict__ gamma, const float* __restrict__ beta,
    float* __restrict__ out) {
  const int tid = threadIdx.x;
  const int rh = tid >> 7;  // row half (0/1)
  const int q = tid & 127;  // float4 index within row
  const int row = blockIdx.x * 2 + rh;
  __shared__ float redS[4], redQ[4];

  const float4 xv = *(const float4*)(x + (size_t)row * H + q * 4);
  const ushort4 pv = *(const ushort4*)(proj + (size_t)row * H + q * 4);
  float y[4] = {xv.x + bf2f(pv.x), xv.y + bf2f(pv.y), xv.z + bf2f(pv.z),
                xv.w + bf2f(pv.w)};
  float ls = y[0] + y[1] + y[2] + y[3];
  float lq = y[0] * y[0] + y[1] * y[1] + y[2] * y[2] + y[3] * y[3];
#pragma unroll
  for (int off = 32; off > 0; off >>= 1) {
    ls += __shfl_xor(ls, off, 64);
    lq += __shfl_xor(lq, off, 64);
  }
  const int wave = tid >> 6, lane = tid & 63;
  if (lane == 0) {
    redS[wave] = ls;
    redQ[wave] = lq;
  }
  __syncthreads();
  const float sum = redS[rh * 2] + redS[rh * 2 + 1];
  const float sq = redQ[rh * 2] + redQ[rh * 2 + 1];
  const float mu = sum * (1.f / H);
  const float var = sq * (1.f / H) - mu * mu;
  const float inv = rsqrtf(var + 1e-5f);
  const float4 gm = *(const float4*)(gamma + q * 4);
  const float4 bt = *(const float4*)(beta + q * 4);
  float4 o;
  o.x = (y[0] - mu) * inv * gm.x + bt.x;
  o.y = (y[1] - mu) * inv * gm.y + bt.y;
  o.z = (y[2] - mu) * inv * gm.z + bt.z;
  o.w = (y[3] - mu) * inv * gm.w + bt.w;
  *(float4*)(out + (size_t)row * H + q * 4) = o;
}

extern "C" void kernel_launch(void* const* d_in, const int* in_sizes, int n_in,
                              void* d_out, int out_size, void* d_ws,
                              size_t ws_size, hipStream_t stream) {
  const float* x = (const float*)d_in[0];
  const int* mask = (const int*)d_in[1];
  const float* refCov = (const float*)d_in[2];
  const float* Wv = (const float*)d_in[3];
  const float* bv = (const float*)d_in[4];
  const float* W1 = (const float*)d_in[5];
  const float* b1 = (const float*)d_in[6];
  const float* W2 = (const float*)d_in[7];
  const float* b2 = (const float*)d_in[8];
  const float* Wo = (const float*)d_in[9];
  const float* bo = (const float*)d_in[10];
  const float* gamma = (const float*)d_in[11];
  const float* beta = (const float*)d_in[12];
  float* out = (float*)d_out;

  const size_t n_attn = (size_t)B * NH * L * L;  // 8388608 (bf16)
  const size_t n_blh = (size_t)B * L * H;        // 1048576
  const size_t n_w = (size_t)H * H;              // 262144
  unsigned short* attnb = (unsigned short*)d_ws;
  unsigned short* valT = attnb + n_attn;
  unsigned short* ctx = valT + n_blh;
  unsigned short* WvT = ctx + n_blh;
  unsigned short* WoT = WvT + n_w;
  unsigned short* proj = WoT + n_w;  // bf16
  int* jidx = (int*)(proj + n_blh);
  int* nv = jidx + B * L;
  const size_t needed =
      (n_attn + 3 * n_blh + 2 * n_w) * 2 + (B * L + B) * 4;
  if (ws_size < needed) return;

  const int M = B * L;  // 2048

  // 0. compaction + W transposes
  prep_kernel<<<132, 512, 0, stream>>>(mask, jidx, nv, Wv, Wo, WvT, WoT);
  // 1. valT GEMM (blocks 0..511, dispatched first) + scores (512..2559)
  fused_scores_value_kernel<<<512 + 2048, 256, 0, stream>>>(
      refCov, mask, jidx, nv, W1, b1, W2, b2, attnb, x, WvT, bv, valT);
  // 2. ctx = attn @ value  (BK=128)
  attn_value_kernel<<<512, 256, 0, stream>>>(attnb, valT, ctx);
  // 3. proj = ctx @ WoT + bo  (bf16, BK=128, 512 blocks)
  gemm_proj_kernel<<<dim3(8, M / 32), 256, 0, stream>>>(ctx, WoT, bo, proj);
  // 4. out = LN(x + proj)
  residual_ln_kernel<<<M / 2, 256, 0, stream>>>(x, proj, gamma, beta, out);
}